// Round 3
// baseline (142.520 us; speedup 1.0000x reference)
//
#include <hip/hip_runtime.h>
#include <math.h>

// RandomLowRes2D: per-image Gaussian blur (R=15, symmetric pad) + linear
// down/up resample along a per-image runtime axis.
//
// Fusion: low[j] = (1-fr)*s[la] + fr*s[la+1] collapses blur+downsample into a
// single fused filter on img: cw[k] = fmaf(fr, dwe[k], we[k+1]),
// with dwe[k] = we[k] - we[k+1] precomputed.
//
// Round 7:
//  - ax0: cooperative low rows (computed once per block, mode B) but with
//    float4/lane and 2 low rows per pass (2 groups x 2 waves): per low row
//    2 VMEM wave-instructions x taps of 1KB -> ~half round 6's instruction
//    count, ~30% below round 5, zero redundant recompute. Upsample float4,
//    2 output rows per pass (group-uniform position math).
//  - ax1: s_pos2[512] LDS table of clamped i/res (2 exact divs/thread
//    instead of 8); upsample re-derives lo2/fr2 via floor/sub (bit-identical)
//    and reads the table with conflict-free ds_read_b128.
//  - grid transposed to (n_img, 128): dispatch interleaves images so heavy
//    images' blocks don't form the tail.
//  - numerics identical to rounds 4-6 (same FMA order, exact IEEE divides).

#define RR 15
#define TAPS 31
#define SIG_PER_FWHM 0.42466090014400953f  // 1/sqrt(8 ln 2)

__global__ __launch_bounds__(256) void lowres2d_kernel(
    const float* __restrict__ x,
    const float* __restrict__ resolution,
    const int*   __restrict__ axis,
    const float* __restrict__ gap,
    float* __restrict__ out)
{
    const int tid = threadIdx.x;
    const int n   = blockIdx.x;          // image index (x-major: interleave)
    const int bx  = blockIdx.y;          // 0..127

    const float res = resolution[n];
    const int   ax  = axis[n];
    const float gp  = gap[n];

    // ax0 images use 64 blocks of 8 rows; rest exit (block-uniform)
    if (ax == 0 && bx >= 64) return;

    const float sig = fmaxf(res * gp * SIG_PER_FWHM, 1e-6f);
    int n_low = (int)floorf(512.0f / res);
    if (n_low < 1) n_low = 1;
    if (n_low > 512) n_low = 512;
    const float nlm1f = (float)(n_low - 1);

    // adaptive radius: normalized weights < 1e-6 outside +-kr (sum >= 1)
    int kr = (int)(sig * 5.2565f) + 1;
    if (kr > RR) kr = RR;
    const int k0 = RR - kr, k1 = RR + 1 + kr;   // fused window k in [k0, k1]
    const int la_lo = kr, la_hi = 510 - kr;     // interior: no reflect needed

    // wd[k] = { we[k+1], dwe[k] }, k = 0..31; we[0]=we[32]=0 implicit
    __shared__ float2 wd[32];
    // overlaid scratch:
    //   ax1: s_img[4][520] (2080) + s_low[4][516] (2064) + s_pos2[512] = 4656
    //   ax0: s_lowB[9][512] = 4608
    __shared__ float smem[4656];
    float (*s_img)[520]  = (float (*)[520])smem;
    float (*s_low)[516]  = (float (*)[516])(smem + 2080);
    float *s_pos2        = smem + 4144;            // 16B-aligned (4144 % 4 == 0)
    float (*s_lowB)[512] = (float (*)[512])smem;

    if (tid < 32) {
        const int k = tid;
        float r = 0.0f;
        if (k < TAPS) {
            float d = (float)(k - RR) / sig;
            r = expf(-0.5f * d * d);
        }
        float tot = r;
        tot += __shfl_xor(tot, 1, 32);
        tot += __shfl_xor(tot, 2, 32);
        tot += __shfl_xor(tot, 4, 32);
        tot += __shfl_xor(tot, 8, 32);
        tot += __shfl_xor(tot, 16, 32);
        float rm1 = __shfl_up(r, 1, 32);
        if (k == 0) rm1 = 0.0f;
        const float inv = 1.0f / tot;            // tot >= 1 (center tap)
        wd[k] = make_float2(r * inv, (rm1 - r) * inv);
    }
    __syncthreads();

    const size_t base = (size_t)n * (512 * 512);
    const float* img = x + base;
    float* o = out + base;

    if (ax == 0) {
        // ---- ax0: cooperative low rows, float4/lane, 2 rows per pass ----
        const int i0 = bx * 8;
        const int g  = tid >> 7;                 // group 0/1 (2 waves each)
        const int lt = tid & 127;                // float4 column
        const float4* img4 = (const float4*)img;
        float4* out4 = (float4*)o;

        // needed low rows for output rows [i0, i0+8)
        float pA = fminf((float)i0 / res, nlm1f);
        int jlo = (int)floorf(pA);
        float pB = fminf((float)(i0 + 7) / res, nlm1f);
        int jhi = (int)floorf(pB) + 1;
        if (jhi > n_low - 1) jhi = n_low - 1;
        if (jhi < jlo) jhi = jlo;
        const int nrows = jhi - jlo + 1;         // <= 9 (res >= 1)

        for (int p = 0; p < nrows; p += 2) {     // block-uniform loop
            int rowoff = p + g;                  // group-uniform
            int j = jlo + ((rowoff < nrows) ? rowoff : (nrows - 1));
            float pos = fminf((float)j * res, 511.0f);
            float lof = floorf(pos);
            float fr  = pos - lof;
            int   la  = __builtin_amdgcn_readfirstlane((int)lof);
            float4 acc = make_float4(0.0f, 0.0f, 0.0f, 0.0f);
            if (la >= la_lo && la <= la_hi) {    // wave-uniform branch
                #pragma unroll 4
                for (int k = k0; k <= k1; ++k) {
                    int t = la - RR + k;         // scalar
                    float2 w = wd[k];
                    float cw = fmaf(fr, w.y, w.x);
                    float4 v = img4[(size_t)(t * 128 + lt)];
                    acc.x = fmaf(cw, v.x, acc.x);
                    acc.y = fmaf(cw, v.y, acc.y);
                    acc.z = fmaf(cw, v.z, acc.z);
                    acc.w = fmaf(cw, v.w, acc.w);
                }
            } else {
                for (int k = k0; k <= k1; ++k) {
                    int t = la - RR + k;
                    t = (t < 0)   ? (-1 - t)   : t;  // symmetric reflect
                    t = (t > 511) ? (1023 - t) : t;
                    float2 w = wd[k];
                    float cw = fmaf(fr, w.y, w.x);
                    float4 v = img4[(size_t)(t * 128 + lt)];
                    acc.x = fmaf(cw, v.x, acc.x);
                    acc.y = fmaf(cw, v.y, acc.y);
                    acc.z = fmaf(cw, v.z, acc.z);
                    acc.w = fmaf(cw, v.w, acc.w);
                }
            }
            if (rowoff < nrows) {                // group-uniform guard
                ((float4*)&s_lowB[rowoff][0])[lt] = acc;
            }
        }
        __syncthreads();

        // upsample: 2 output rows per pass, group-uniform position math
        #pragma unroll
        for (int p = 0; p < 4; ++p) {
            int i = i0 + p * 2 + g;              // group-uniform
            float pos2 = fminf((float)i / res, nlm1f);  // exact IEEE div
            float l2f  = floorf(pos2);
            float fr2  = pos2 - l2f;
            int lo2 = (int)l2f;                  // in [jlo, jhi]
            int hi2 = (lo2 + 1 <= jhi) ? (lo2 + 1) : jhi;  // == min(lo2+1, n_low-1)
            float4 A = ((float4*)&s_lowB[lo2 - jlo][0])[lt];
            float4 B = ((float4*)&s_lowB[hi2 - jlo][0])[lt];
            float omf2 = 1.0f - fr2;
            float4 ov;
            ov.x = A.x * omf2 + B.x * fr2;
            ov.y = A.y * omf2 + B.y * fr2;
            ov.z = A.z * omf2 + B.z * fr2;
            ov.w = A.w * omf2 + B.w * fr2;
            out4[(size_t)(i * 128 + lt)] = ov;
        }
    } else {
        // ---------------- ax1: LDS-tiled 4 rows, coalesced ----------------
        const int h0 = bx * 4;

        // load 4x512 tile, float4 coalesced (512 float4 over 256 threads)
        const float4* img4 = (const float4*)(img + (size_t)h0 * 512);
        #pragma unroll
        for (int p = 0; p < 2; ++p) {
            int m = p * 256 + tid;
            int r = m >> 7, c4 = m & 127;
            ((float4*)&s_img[r][0])[c4] = img4[r * 128 + c4];
        }
        // upsample position table: clamped i/res (exact div), 2 per thread
        #pragma unroll
        for (int p = 0; p < 2; ++p) {
            int m = p * 256 + tid;
            s_pos2[m] = fminf((float)m / res, nlm1f);
        }
        __syncthreads();

        // compute lows: one wave per row (r uniform per wave), j strided 64
        {
            const int r = __builtin_amdgcn_readfirstlane(tid >> 6);
            for (int j = (tid & 63); j < n_low; j += 64) {
                float pos = fminf((float)j * res, 511.0f);
                float lof = floorf(pos);
                float fr  = pos - lof;
                int   la  = (int)lof;
                float acc = 0.0f;
                if (la >= la_lo && la <= la_hi) {
                    #pragma unroll 4
                    for (int k = k0; k <= k1; ++k) {
                        int t = la - RR + k;
                        float2 w = wd[k];
                        float cw = fmaf(fr, w.y, w.x);
                        acc = fmaf(cw, s_img[r][t], acc);
                    }
                } else {
                    for (int k = k0; k <= k1; ++k) {
                        int t = la - RR + k;
                        t = (t < 0)   ? (-1 - t)   : t;
                        t = (t > 511) ? (1023 - t) : t;
                        float2 w = wd[k];
                        float cw = fmaf(fr, w.y, w.x);
                        acc = fmaf(cw, s_img[r][t], acc);
                    }
                }
                s_low[r][j] = acc;
            }
        }
        __syncthreads();

        // upsample + coalesced float4 stores (positions from table)
        float4* out4 = (float4*)(o + (size_t)h0 * 512);
        #pragma unroll
        for (int p = 0; p < 2; ++p) {
            int m = p * 256 + tid;
            int r = m >> 7, c4 = m & 127;
            float4 p2 = ((const float4*)s_pos2)[c4];
            float p2a[4] = {p2.x, p2.y, p2.z, p2.w};
            float vals[4];
            #pragma unroll
            for (int q = 0; q < 4; ++q) {
                float pos2 = p2a[q];
                float l2f  = floorf(pos2);
                float fr2  = pos2 - l2f;
                int lo2 = (int)l2f;              // <= n_low-1 (table clamped)
                int hi2 = (lo2 + 1 < n_low) ? (lo2 + 1) : (n_low - 1);
                vals[q] = s_low[r][lo2] * (1.0f - fr2) + s_low[r][hi2] * fr2;
            }
            float4 ov;
            ov.x = vals[0]; ov.y = vals[1]; ov.z = vals[2]; ov.w = vals[3];
            out4[r * 128 + c4] = ov;
        }
    }
}

extern "C" void kernel_launch(void* const* d_in, const int* in_sizes, int n_in,
                              void* d_out, int out_size, void* d_ws, size_t ws_size,
                              hipStream_t stream) {
    const float* x          = (const float*)d_in[0];
    const float* resolution = (const float*)d_in[1];
    const int*   axis       = (const int*)d_in[2];
    const float* gap        = (const float*)d_in[3];
    float* out = (float*)d_out;

    const int n_img = in_sizes[1];   // B*C = 64

    dim3 grid(n_img, 128);           // x-major: images interleave in dispatch
    lowres2d_kernel<<<grid, 256, 0, stream>>>(x, resolution, axis, gap, out);
}

// Round 4
// 125.927 us; speedup vs baseline: 1.1318x; 1.1318x over previous
//
#include <hip/hip_runtime.h>
#include <math.h>

// RandomLowRes2D: per-image Gaussian blur (R=15, symmetric pad) + linear
// down/up resample along a per-image runtime axis.
//
// Fusion: low[j] = (1-fr)*s[la] + fr*s[la+1] collapses blur+downsample into a
// single fused filter on img: cw[k] = fmaf(fr, dwe[k], we[k+1]),
// with dwe[k] = we[k] - we[k+1] precomputed.
//
// Round 8: REVERT the round-7 grid transpose (single-variable experiment).
//  - Grid back to (128, n_img), bx = blockIdx.x: blocks of one image are
//    contiguous in dispatch order. Round 7's image-interleaved order ran 64
//    concurrent 1MB streams -> DRAM row thrash; FETCH dropped (L2 absorbed
//    more) but per-miss latency rose and this kernel is latency-bound:
//    56 us vs 45. Sequential per-image streaming is the fast order.
//  - Keeps round 7's ax0 (cooperative low rows, float4/lane, 2 rows/pass,
//    zero recompute) and ax1 pos2 table (2 divides/thread instead of 8).
//  - numerics identical to rounds 4-7 (same FMA order, exact IEEE divides).

#define RR 15
#define TAPS 31
#define SIG_PER_FWHM 0.42466090014400953f  // 1/sqrt(8 ln 2)

__global__ __launch_bounds__(256) void lowres2d_kernel(
    const float* __restrict__ x,
    const float* __restrict__ resolution,
    const int*   __restrict__ axis,
    const float* __restrict__ gap,
    float* __restrict__ out)
{
    const int tid = threadIdx.x;
    const int n   = blockIdx.y;          // image index
    const int bx  = blockIdx.x;          // 0..127 (image-contiguous dispatch)

    const float res = resolution[n];
    const int   ax  = axis[n];
    const float gp  = gap[n];

    // ax0 images use 64 blocks of 8 rows; rest exit (block-uniform)
    if (ax == 0 && bx >= 64) return;

    const float sig = fmaxf(res * gp * SIG_PER_FWHM, 1e-6f);
    int n_low = (int)floorf(512.0f / res);
    if (n_low < 1) n_low = 1;
    if (n_low > 512) n_low = 512;
    const float nlm1f = (float)(n_low - 1);

    // adaptive radius: normalized weights < 1e-6 outside +-kr (sum >= 1)
    int kr = (int)(sig * 5.2565f) + 1;
    if (kr > RR) kr = RR;
    const int k0 = RR - kr, k1 = RR + 1 + kr;   // fused window k in [k0, k1]
    const int la_lo = kr, la_hi = 510 - kr;     // interior: no reflect needed

    // wd[k] = { we[k+1], dwe[k] }, k = 0..31; we[0]=we[32]=0 implicit
    __shared__ float2 wd[32];
    // overlaid scratch:
    //   ax1: s_img[4][520] (2080) + s_low[4][516] (2064) + s_pos2[512] = 4656
    //   ax0: s_lowB[9][512] = 4608
    __shared__ float smem[4656];
    float (*s_img)[520]  = (float (*)[520])smem;
    float (*s_low)[516]  = (float (*)[516])(smem + 2080);
    float *s_pos2        = smem + 4144;            // 16B-aligned (4144 % 4 == 0)
    float (*s_lowB)[512] = (float (*)[512])smem;

    if (tid < 32) {
        const int k = tid;
        float r = 0.0f;
        if (k < TAPS) {
            float d = (float)(k - RR) / sig;
            r = expf(-0.5f * d * d);
        }
        float tot = r;
        tot += __shfl_xor(tot, 1, 32);
        tot += __shfl_xor(tot, 2, 32);
        tot += __shfl_xor(tot, 4, 32);
        tot += __shfl_xor(tot, 8, 32);
        tot += __shfl_xor(tot, 16, 32);
        float rm1 = __shfl_up(r, 1, 32);
        if (k == 0) rm1 = 0.0f;
        const float inv = 1.0f / tot;            // tot >= 1 (center tap)
        wd[k] = make_float2(r * inv, (rm1 - r) * inv);
    }
    __syncthreads();

    const size_t base = (size_t)n * (512 * 512);
    const float* img = x + base;
    float* o = out + base;

    if (ax == 0) {
        // ---- ax0: cooperative low rows, float4/lane, 2 rows per pass ----
        const int i0 = bx * 8;
        const int g  = tid >> 7;                 // group 0/1 (2 waves each)
        const int lt = tid & 127;                // float4 column
        const float4* img4 = (const float4*)img;
        float4* out4 = (float4*)o;

        // needed low rows for output rows [i0, i0+8)
        float pA = fminf((float)i0 / res, nlm1f);
        int jlo = (int)floorf(pA);
        float pB = fminf((float)(i0 + 7) / res, nlm1f);
        int jhi = (int)floorf(pB) + 1;
        if (jhi > n_low - 1) jhi = n_low - 1;
        if (jhi < jlo) jhi = jlo;
        const int nrows = jhi - jlo + 1;         // <= 9 (res >= 1)

        for (int p = 0; p < nrows; p += 2) {     // block-uniform loop
            int rowoff = p + g;                  // group-uniform
            int j = jlo + ((rowoff < nrows) ? rowoff : (nrows - 1));
            float pos = fminf((float)j * res, 511.0f);
            float lof = floorf(pos);
            float fr  = pos - lof;
            int   la  = __builtin_amdgcn_readfirstlane((int)lof);
            float4 acc = make_float4(0.0f, 0.0f, 0.0f, 0.0f);
            if (la >= la_lo && la <= la_hi) {    // wave-uniform branch
                #pragma unroll 4
                for (int k = k0; k <= k1; ++k) {
                    int t = la - RR + k;         // scalar
                    float2 w = wd[k];
                    float cw = fmaf(fr, w.y, w.x);
                    float4 v = img4[(size_t)(t * 128 + lt)];
                    acc.x = fmaf(cw, v.x, acc.x);
                    acc.y = fmaf(cw, v.y, acc.y);
                    acc.z = fmaf(cw, v.z, acc.z);
                    acc.w = fmaf(cw, v.w, acc.w);
                }
            } else {
                for (int k = k0; k <= k1; ++k) {
                    int t = la - RR + k;
                    t = (t < 0)   ? (-1 - t)   : t;  // symmetric reflect
                    t = (t > 511) ? (1023 - t) : t;
                    float2 w = wd[k];
                    float cw = fmaf(fr, w.y, w.x);
                    float4 v = img4[(size_t)(t * 128 + lt)];
                    acc.x = fmaf(cw, v.x, acc.x);
                    acc.y = fmaf(cw, v.y, acc.y);
                    acc.z = fmaf(cw, v.z, acc.z);
                    acc.w = fmaf(cw, v.w, acc.w);
                }
            }
            if (rowoff < nrows) {                // group-uniform guard
                ((float4*)&s_lowB[rowoff][0])[lt] = acc;
            }
        }
        __syncthreads();

        // upsample: 2 output rows per pass, group-uniform position math
        #pragma unroll
        for (int p = 0; p < 4; ++p) {
            int i = i0 + p * 2 + g;              // group-uniform
            float pos2 = fminf((float)i / res, nlm1f);  // exact IEEE div
            float l2f  = floorf(pos2);
            float fr2  = pos2 - l2f;
            int lo2 = (int)l2f;                  // in [jlo, jhi]
            int hi2 = (lo2 + 1 <= jhi) ? (lo2 + 1) : jhi;  // == min(lo2+1, n_low-1)
            float4 A = ((float4*)&s_lowB[lo2 - jlo][0])[lt];
            float4 B = ((float4*)&s_lowB[hi2 - jlo][0])[lt];
            float omf2 = 1.0f - fr2;
            float4 ov;
            ov.x = A.x * omf2 + B.x * fr2;
            ov.y = A.y * omf2 + B.y * fr2;
            ov.z = A.z * omf2 + B.z * fr2;
            ov.w = A.w * omf2 + B.w * fr2;
            out4[(size_t)(i * 128 + lt)] = ov;
        }
    } else {
        // ---------------- ax1: LDS-tiled 4 rows, coalesced ----------------
        const int h0 = bx * 4;

        // load 4x512 tile, float4 coalesced (512 float4 over 256 threads)
        const float4* img4 = (const float4*)(img + (size_t)h0 * 512);
        #pragma unroll
        for (int p = 0; p < 2; ++p) {
            int m = p * 256 + tid;
            int r = m >> 7, c4 = m & 127;
            ((float4*)&s_img[r][0])[c4] = img4[r * 128 + c4];
        }
        // upsample position table: clamped i/res (exact div), 2 per thread
        #pragma unroll
        for (int p = 0; p < 2; ++p) {
            int m = p * 256 + tid;
            s_pos2[m] = fminf((float)m / res, nlm1f);
        }
        __syncthreads();

        // compute lows: one wave per row (r uniform per wave), j strided 64
        {
            const int r = __builtin_amdgcn_readfirstlane(tid >> 6);
            for (int j = (tid & 63); j < n_low; j += 64) {
                float pos = fminf((float)j * res, 511.0f);
                float lof = floorf(pos);
                float fr  = pos - lof;
                int   la  = (int)lof;
                float acc = 0.0f;
                if (la >= la_lo && la <= la_hi) {
                    #pragma unroll 4
                    for (int k = k0; k <= k1; ++k) {
                        int t = la - RR + k;
                        float2 w = wd[k];
                        float cw = fmaf(fr, w.y, w.x);
                        acc = fmaf(cw, s_img[r][t], acc);
                    }
                } else {
                    for (int k = k0; k <= k1; ++k) {
                        int t = la - RR + k;
                        t = (t < 0)   ? (-1 - t)   : t;
                        t = (t > 511) ? (1023 - t) : t;
                        float2 w = wd[k];
                        float cw = fmaf(fr, w.y, w.x);
                        acc = fmaf(cw, s_img[r][t], acc);
                    }
                }
                s_low[r][j] = acc;
            }
        }
        __syncthreads();

        // upsample + coalesced float4 stores (positions from table)
        float4* out4 = (float4*)(o + (size_t)h0 * 512);
        #pragma unroll
        for (int p = 0; p < 2; ++p) {
            int m = p * 256 + tid;
            int r = m >> 7, c4 = m & 127;
            float4 p2 = ((const float4*)s_pos2)[c4];
            float p2a[4] = {p2.x, p2.y, p2.z, p2.w};
            float vals[4];
            #pragma unroll
            for (int q = 0; q < 4; ++q) {
                float pos2 = p2a[q];
                float l2f  = floorf(pos2);
                float fr2  = pos2 - l2f;
                int lo2 = (int)l2f;              // <= n_low-1 (table clamped)
                int hi2 = (lo2 + 1 < n_low) ? (lo2 + 1) : (n_low - 1);
                vals[q] = s_low[r][lo2] * (1.0f - fr2) + s_low[r][hi2] * fr2;
            }
            float4 ov;
            ov.x = vals[0]; ov.y = vals[1]; ov.z = vals[2]; ov.w = vals[3];
            out4[r * 128 + c4] = ov;
        }
    }
}

extern "C" void kernel_launch(void* const* d_in, const int* in_sizes, int n_in,
                              void* d_out, int out_size, void* d_ws, size_t ws_size,
                              hipStream_t stream) {
    const float* x          = (const float*)d_in[0];
    const float* resolution = (const float*)d_in[1];
    const int*   axis       = (const int*)d_in[2];
    const float* gap        = (const float*)d_in[3];
    float* out = (float*)d_out;

    const int n_img = in_sizes[1];   // B*C = 64

    dim3 grid(128, n_img);           // bx fastest: per-image sequential streaming
    lowres2d_kernel<<<grid, 256, 0, stream>>>(x, resolution, axis, gap, out);
}

// Round 5
// 124.528 us; speedup vs baseline: 1.1445x; 1.0112x over previous
//
#include <hip/hip_runtime.h>
#include <math.h>

// RandomLowRes2D: per-image Gaussian blur (R=15, symmetric pad) + linear
// down/up resample along a per-image runtime axis.
//
// Fusion: low[j] = (1-fr)*s[la] + fr*s[la+1] collapses blur+downsample into a
// single fused filter on img: cw[k] = fmaf(fr, dwe[k], we[k+1]),
// with dwe[k] = we[k] - we[k+1] precomputed.
//
// Round 9 (ax1 row-amortization — ax1 was ~2.5x ax0's instr per element):
//  - ax1 low phase: ONE thread computes low column j for ALL 4 tile rows
//    (j = tid, stride 256). The wd[k] LDS read + cw FMA now serve 4 output
//    elements instead of 1 (old code had 4 waves each redoing them per row).
//    4 independent accumulator chains also deepen ILP.
//  - ax1 upsample: one thread owns column i (2 cols): pos2/lo2/fr2 position
//    math computed once per column for 4 rows (was once per element);
//    4 coalesced scalar stores per column. s_pos2 table dropped.
//  - ax0 path and grid order unchanged from round 8 (kernel ~39us measured).
//  - numerics identical (same FMA order / contraction, exact IEEE divides).

#define RR 15
#define TAPS 31
#define SIG_PER_FWHM 0.42466090014400953f  // 1/sqrt(8 ln 2)

__global__ __launch_bounds__(256) void lowres2d_kernel(
    const float* __restrict__ x,
    const float* __restrict__ resolution,
    const int*   __restrict__ axis,
    const float* __restrict__ gap,
    float* __restrict__ out)
{
    const int tid = threadIdx.x;
    const int n   = blockIdx.y;          // image index
    const int bx  = blockIdx.x;          // 0..127 (image-contiguous dispatch)

    const float res = resolution[n];
    const int   ax  = axis[n];
    const float gp  = gap[n];

    // ax0 images use 64 blocks of 8 rows; rest exit (block-uniform)
    if (ax == 0 && bx >= 64) return;

    const float sig = fmaxf(res * gp * SIG_PER_FWHM, 1e-6f);
    int n_low = (int)floorf(512.0f / res);
    if (n_low < 1) n_low = 1;
    if (n_low > 512) n_low = 512;
    const float nlm1f = (float)(n_low - 1);

    // adaptive radius: normalized weights < 1e-6 outside +-kr (sum >= 1)
    int kr = (int)(sig * 5.2565f) + 1;
    if (kr > RR) kr = RR;
    const int k0 = RR - kr, k1 = RR + 1 + kr;   // fused window k in [k0, k1]
    const int la_lo = kr, la_hi = 510 - kr;     // interior: no reflect needed

    // wd[k] = { we[k+1], dwe[k] }, k = 0..31; we[0]=we[32]=0 implicit
    __shared__ float2 wd[32];
    // overlaid scratch:
    //   ax1: s_img[4][520] (2080) + s_low[4][516] (2064) = 4144
    //   ax0: s_lowB[9][512] = 4608
    __shared__ float smem[4608];
    float (*s_img)[520]  = (float (*)[520])smem;
    float (*s_low)[516]  = (float (*)[516])(smem + 2080);
    float (*s_lowB)[512] = (float (*)[512])smem;

    if (tid < 32) {
        const int k = tid;
        float r = 0.0f;
        if (k < TAPS) {
            float d = (float)(k - RR) / sig;
            r = expf(-0.5f * d * d);
        }
        float tot = r;
        tot += __shfl_xor(tot, 1, 32);
        tot += __shfl_xor(tot, 2, 32);
        tot += __shfl_xor(tot, 4, 32);
        tot += __shfl_xor(tot, 8, 32);
        tot += __shfl_xor(tot, 16, 32);
        float rm1 = __shfl_up(r, 1, 32);
        if (k == 0) rm1 = 0.0f;
        const float inv = 1.0f / tot;            // tot >= 1 (center tap)
        wd[k] = make_float2(r * inv, (rm1 - r) * inv);
    }
    __syncthreads();

    const size_t base = (size_t)n * (512 * 512);
    const float* img = x + base;
    float* o = out + base;

    if (ax == 0) {
        // ---- ax0: cooperative low rows, float4/lane, 2 rows per pass ----
        const int i0 = bx * 8;
        const int g  = tid >> 7;                 // group 0/1 (2 waves each)
        const int lt = tid & 127;                // float4 column
        const float4* img4 = (const float4*)img;
        float4* out4 = (float4*)o;

        // needed low rows for output rows [i0, i0+8)
        float pA = fminf((float)i0 / res, nlm1f);
        int jlo = (int)floorf(pA);
        float pB = fminf((float)(i0 + 7) / res, nlm1f);
        int jhi = (int)floorf(pB) + 1;
        if (jhi > n_low - 1) jhi = n_low - 1;
        if (jhi < jlo) jhi = jlo;
        const int nrows = jhi - jlo + 1;         // <= 9 (res >= 1)

        for (int p = 0; p < nrows; p += 2) {     // block-uniform loop
            int rowoff = p + g;                  // group-uniform
            int j = jlo + ((rowoff < nrows) ? rowoff : (nrows - 1));
            float pos = fminf((float)j * res, 511.0f);
            float lof = floorf(pos);
            float fr  = pos - lof;
            int   la  = __builtin_amdgcn_readfirstlane((int)lof);
            float4 acc = make_float4(0.0f, 0.0f, 0.0f, 0.0f);
            if (la >= la_lo && la <= la_hi) {    // wave-uniform branch
                #pragma unroll 4
                for (int k = k0; k <= k1; ++k) {
                    int t = la - RR + k;         // scalar
                    float2 w = wd[k];
                    float cw = fmaf(fr, w.y, w.x);
                    float4 v = img4[(size_t)(t * 128 + lt)];
                    acc.x = fmaf(cw, v.x, acc.x);
                    acc.y = fmaf(cw, v.y, acc.y);
                    acc.z = fmaf(cw, v.z, acc.z);
                    acc.w = fmaf(cw, v.w, acc.w);
                }
            } else {
                for (int k = k0; k <= k1; ++k) {
                    int t = la - RR + k;
                    t = (t < 0)   ? (-1 - t)   : t;  // symmetric reflect
                    t = (t > 511) ? (1023 - t) : t;
                    float2 w = wd[k];
                    float cw = fmaf(fr, w.y, w.x);
                    float4 v = img4[(size_t)(t * 128 + lt)];
                    acc.x = fmaf(cw, v.x, acc.x);
                    acc.y = fmaf(cw, v.y, acc.y);
                    acc.z = fmaf(cw, v.z, acc.z);
                    acc.w = fmaf(cw, v.w, acc.w);
                }
            }
            if (rowoff < nrows) {                // group-uniform guard
                ((float4*)&s_lowB[rowoff][0])[lt] = acc;
            }
        }
        __syncthreads();

        // upsample: 2 output rows per pass, group-uniform position math
        #pragma unroll
        for (int p = 0; p < 4; ++p) {
            int i = i0 + p * 2 + g;              // group-uniform
            float pos2 = fminf((float)i / res, nlm1f);  // exact IEEE div
            float l2f  = floorf(pos2);
            float fr2  = pos2 - l2f;
            int lo2 = (int)l2f;                  // in [jlo, jhi]
            int hi2 = (lo2 + 1 <= jhi) ? (lo2 + 1) : jhi;  // == min(lo2+1, n_low-1)
            float4 A = ((float4*)&s_lowB[lo2 - jlo][0])[lt];
            float4 B = ((float4*)&s_lowB[hi2 - jlo][0])[lt];
            float omf2 = 1.0f - fr2;
            float4 ov;
            ov.x = A.x * omf2 + B.x * fr2;
            ov.y = A.y * omf2 + B.y * fr2;
            ov.z = A.z * omf2 + B.z * fr2;
            ov.w = A.w * omf2 + B.w * fr2;
            out4[(size_t)(i * 128 + lt)] = ov;
        }
    } else {
        // ---------------- ax1: LDS-tiled 4 rows, row-amortized ------------
        const int h0 = bx * 4;

        // load 4x512 tile, float4 coalesced (512 float4 over 256 threads)
        const float4* img4 = (const float4*)(img + (size_t)h0 * 512);
        #pragma unroll
        for (int p = 0; p < 2; ++p) {
            int m = p * 256 + tid;
            int r = m >> 7, c4 = m & 127;
            ((float4*)&s_img[r][0])[c4] = img4[r * 128 + c4];
        }
        __syncthreads();

        // low phase: one thread per low column j, ALL 4 rows per thread.
        // wd[k] read + cw FMA amortized over 4 elements; 4 FMA chains (ILP).
        for (int j = tid; j < n_low; j += 256) {
            float pos = fminf((float)j * res, 511.0f);
            float lof = floorf(pos);
            float fr  = pos - lof;
            int   la  = (int)lof;
            float a0 = 0.0f, a1 = 0.0f, a2 = 0.0f, a3 = 0.0f;
            if (la >= la_lo && la <= la_hi) {
                #pragma unroll 4
                for (int k = k0; k <= k1; ++k) {
                    int t = la - RR + k;
                    float2 w = wd[k];
                    float cw = fmaf(fr, w.y, w.x);
                    a0 = fmaf(cw, s_img[0][t], a0);
                    a1 = fmaf(cw, s_img[1][t], a1);
                    a2 = fmaf(cw, s_img[2][t], a2);
                    a3 = fmaf(cw, s_img[3][t], a3);
                }
            } else {
                for (int k = k0; k <= k1; ++k) {
                    int t = la - RR + k;
                    t = (t < 0)   ? (-1 - t)   : t;  // symmetric reflect
                    t = (t > 511) ? (1023 - t) : t;
                    float2 w = wd[k];
                    float cw = fmaf(fr, w.y, w.x);
                    a0 = fmaf(cw, s_img[0][t], a0);
                    a1 = fmaf(cw, s_img[1][t], a1);
                    a2 = fmaf(cw, s_img[2][t], a2);
                    a3 = fmaf(cw, s_img[3][t], a3);
                }
            }
            s_low[0][j] = a0;
            s_low[1][j] = a1;
            s_low[2][j] = a2;
            s_low[3][j] = a3;
        }
        __syncthreads();

        // upsample: one thread per column i (2 cols); pos math once per
        // column serves 4 rows; coalesced scalar stores.
        #pragma unroll
        for (int p = 0; p < 2; ++p) {
            int i = p * 256 + tid;
            float pos2 = fminf((float)i / res, nlm1f);  // exact IEEE div
            float l2f  = floorf(pos2);
            float fr2  = pos2 - l2f;
            int lo2 = (int)l2f;                  // <= n_low-1 (pos2 clamped)
            int hi2 = (lo2 + 1 < n_low) ? (lo2 + 1) : (n_low - 1);
            float omf2 = 1.0f - fr2;
            #pragma unroll
            for (int r = 0; r < 4; ++r) {
                float v = s_low[r][lo2] * omf2 + s_low[r][hi2] * fr2;
                o[(size_t)(h0 + r) * 512 + i] = v;
            }
        }
    }
}

extern "C" void kernel_launch(void* const* d_in, const int* in_sizes, int n_in,
                              void* d_out, int out_size, void* d_ws, size_t ws_size,
                              hipStream_t stream) {
    const float* x          = (const float*)d_in[0];
    const float* resolution = (const float*)d_in[1];
    const int*   axis       = (const int*)d_in[2];
    const float* gap        = (const float*)d_in[3];
    float* out = (float*)d_out;

    const int n_img = in_sizes[1];   // B*C = 64

    dim3 grid(128, n_img);           // bx fastest: per-image sequential streaming
    lowres2d_kernel<<<grid, 256, 0, stream>>>(x, resolution, axis, gap, out);
}